// Round 11
// baseline (364.368 us; speedup 1.0000x reference)
//
#include <hip/hip_runtime.h>
#include <hip/hip_bf16.h>
#include <math.h>

// ============================================================================
// MinimalNetwork, round 25: occupancy re-test in the barrier-free regime.
// r24 post-mortem: fused 250->212 (barrier-free + frag-contiguous weights),
// conflicts 12.3M->3.45M. Still latency-bound (VALU 31/MFMA 7/HBM 3) at
// 2 waves/SIMD. All prior occupancy tests (r17) ran under per-phase block
// barriers (waves stall together -> occupancy useless); the loop is now
// barrier-free, so extra waves should fill stall slots directly.
// Changes vs r24:
//   - C3 read from global in kv_sec (r17/r18-proven; 4.9KB L1-resident).
//     LDS 58916 -> 54016 B -> __launch_bounds__(256,3) = 3 blk/CU.
//   - c3_combined + prep_combined merged into init_kernel (block-role split).
// Kill: fused >=200us at ~28% occupancy -> occupancy is not the lever;
// remaining gap = serial kv/consume chain -> assess structural floor.
// ============================================================================

#define FEATD 72
#define NCOL 1216
#define SWISH_SCALE 1.679177f

typedef __attribute__((ext_vector_type(8))) short bf16x8;
typedef __attribute__((ext_vector_type(4))) float f32x4;

// ---- 19 (lo,li,lf) chunks; CB_OFF = offsets into the C3 coefficient pool ----
constexpr int NCOMBO = 19;
constexpr int CB_LO[NCOMBO] = {0,0,0,1,1,1,1,1,1,1,2,2,2,2,2,2,2,2,2};
constexpr int CB_LI[NCOMBO] = {0,1,2,0,1,1,1,2,2,2,0,1,1,1,2,2,2,2,2};
constexpr int CB_LF[NCOMBO] = {0,1,2,1,0,1,2,1,2,3,2,1,2,3,0,1,2,3,4};
constexpr int CB_OFF[NCOMBO] = {0,1,10,35,44,53,80,125,170,245,350,375,420,495,600,625,700,825,1000};
constexpr int CB_SZ[NCOMBO]  = {1,9,25,9,9,27,45,45,75,105,25,45,75,105,25,75,125,175,225};
constexpr int C3TOT = 1225;

constexpr int C3OFFT[3][3][5] = {
  { {0,-1,-1,-1,-1}, {-1,1,-1,-1,-1}, {-1,-1,10,-1,-1} },
  { {-1,35,-1,-1,-1}, {44,53,80,-1,-1}, {-1,125,170,245,-1} },
  { {-1,-1,350,-1,-1}, {-1,375,420,495,-1}, {600,625,700,825,1000} }
};
constexpr int ROFFT[3][3] = {{0,64,128},{192,256,448},{640,704,896}};
constexpr int FOFFT[3]   = {0,8,32};

__device__ const double d_fact[11] = {1.,1.,2.,6.,24.,120.,720.,5040.,40320.,362880.,3628800.};

// ---------------------------------------------------------------------------
// Wigner 3j (complex basis, Racah) in double precision + real change of basis
// ---------------------------------------------------------------------------
__device__ double w3j_entry(int j1,int j2,int j3,int m1,int m2,int m3){
  if (m1+m2+m3 != 0) return 0.0;
  int dj = j1-j2; if (dj<0) dj=-dj;
  if (j3 < dj || j3 > j1+j2) return 0.0;
  int t1 = j2 - m1 - j3, t2 = j1 + m2 - j3;
  int kmin = 0; if (t1>kmin) kmin=t1; if (t2>kmin) kmin=t2;
  int kmax = j1+j2-j3; if (j1-m1<kmax) kmax=j1-m1; if (j2+m2<kmax) kmax=j2+m2;
  double s = 0.0;
  for (int k=kmin;k<=kmax;++k){
    double den = d_fact[k]*d_fact[k-t1]*d_fact[k-t2]*d_fact[j1+j2-j3-k]
               * d_fact[j1-m1-k]*d_fact[j2+m2-k];
    s += ((k&1)? -1.0:1.0)/den;
  }
  double pref = sqrt(d_fact[j1+j2-j3]*d_fact[j1-j2+j3]*d_fact[-j1+j2+j3]/d_fact[j1+j2+j3+1]
               * d_fact[j1+m1]*d_fact[j1-m1]*d_fact[j2+m2]*d_fact[j2-m2]
               * d_fact[j3+m3]*d_fact[j3-m3]);
  int ex = j1-j2-m3;
  if (ex & 1) pref = -pref;
  return pref*s;
}

__device__ void cob(int l, int r, int c, double& re, double& im){
  re = 0.0; im = 0.0;
  int mr = r - l, mc = c - l;
  const double s = 0.70710678118654752440;
  if (mr == 0) { if (mc == 0) re = 1.0; return; }
  if (mr > 0) {
    if (mc == mr)       re = (mr & 1) ? -s : s;
    else if (mc == -mr) re = s;
  } else {
    int m = -mr;
    if (mc == -m)      im = s;
    else if (mc == m)  im = (m & 1) ? s : -s;
  }
}

// ---------------------------------------------------------------------------
// Merged init: blocks 0..18 build+normalize one C3 chunk (wave 0 active);
// blocks 19.. repack W3t/W1t/W2t into the fragment-contiguous layout:
//   W3t elem idx = chunk*8192 + ((ct*4+ks)*64 + lane)*8 + j
//     encodes row r = ct*16+(lane&15), k = ks*32+(lane>>4)*8+j.
//   W1t/W2t elem idx = ((ot*4+ks)*64 + lane)*8 + j  (ot=0..6).
// 0.1 scale folded; k>=100 / o>=100 zero-padded.
// ---------------------------------------------------------------------------
__global__ __launch_bounds__(256) void init_kernel(
    const float* __restrict__ W3, const float* __restrict__ W1,
    const float* __restrict__ W2, __hip_bfloat16* __restrict__ W3t,
    __hip_bfloat16* __restrict__ W1t, __hip_bfloat16* __restrict__ W2t,
    float* __restrict__ C3f)
{
  if (blockIdx.x < NCOMBO){
    __shared__ double sre[225], sim[225];
    const int c = blockIdx.x;
    const int lo = CB_LO[c], li = CB_LI[c], lf = CB_LF[c];
    const int off = CB_OFF[c], sz = CB_SZ[c];
    const int n2 = 2*li+1, n3 = 2*lf+1;
    const int t = threadIdx.x;

    if (t < 64){
      for (int p=t; p<sz; p+=64){
        int a = p/(n2*n3), b = (p/n3)%n2, g = p%n3;
        double re=0.0, im=0.0;
        for (int m1=-lo; m1<=lo; ++m1){
          for (int m2=-li; m2<=li; ++m2){
            int m3 = -m1-m2;
            if (m3 < -lf || m3 > lf) continue;
            double w = w3j_entry(lo,li,lf,m1,m2,m3);
            if (w == 0.0) continue;
            double r1,i1,r2,i2,r3,i3;
            cob(lo, a, m1+lo, r1,i1);
            cob(li, b, m2+li, r2,i2);
            cob(lf, g, m3+lf, r3,i3);
            double rr = r1*r2 - i1*i2, ri = r1*i2 + i1*r2;
            double fr = rr*r3 - ri*i3, fi = rr*i3 + ri*r3;
            re += fr*w; im += fi*w;
          }
        }
        sre[p] = re; sim[p] = im;
      }
    }
    __syncthreads();
    if (t < 64){
      double s2r=0.0, s2i=0.0;
      for (int p=t; p<sz; p+=64){ double x=sre[p], y=sim[p]; s2r+=x*x; s2i+=y*y; }
      for (int m=1; m<64; m<<=1){ s2r += __shfl_xor(s2r, m, 64); s2i += __shfl_xor(s2i, m, 64); }
      bool useRe = (s2r >= s2i);
      double n = sqrt(useRe ? s2r : s2i);
      double inv = (n > 0.0) ? 1.0/n : 1.0;
      for (int p=t; p<sz; p+=64){
        double v = useRe ? sre[p] : sim[p];
        C3f[off+p] = (float)(v*inv);
      }
    }
    return;
  }

  int idx = (blockIdx.x - NCOMBO)*256 + threadIdx.x;
  constexpr int NW3 = 19*8192;       // 155648
  constexpr int HALF = 7*4*64*8;     // 14336
  if (idx < NW3){
    int j = idx & 7, lane = (idx>>3)&63, kc = (idx>>9)&15, chunk = idx>>13;
    int ks = kc & 3, ct = kc >> 2;
    int r = ct*16 + (lane&15);
    int k = ks*32 + (lane>>4)*8 + j;
    int lo = CB_LO[chunk], li = CB_LI[chunk], lf = CB_LF[chunk];
    int lmin = lo<li ? lo : li;
    int nlf = 2*lmin+1;
    int fi = lf - (lo>li ? lo-li : li-lo);
    int c = ROFFT[lo][li] + r*nlf + fi;
    float v = (k < 100) ? 0.1f*W3[(size_t)k*NCOL + c] : 0.f;
    W3t[idx] = __float2bfloat16(v);
  } else if (idx < NW3 + 2*HALF){
    int r2 = idx - NW3;
    const float* W = (r2 < HALF) ? W1 : W2;
    __hip_bfloat16* Wt = (r2 < HALF) ? W1t : W2t;
    int r = (r2 < HALF) ? r2 : r2 - HALF;
    int j = r & 7, lane = (r>>3)&63, kc = r>>9;   // kc = ot*4+ks in 0..27
    int ks = kc & 3, ot = kc >> 2;
    int o = ot*16 + (lane&15);
    int k = ks*32 + (lane>>4)*8 + j;
    float v = (o < 100 && k < 100) ? 0.1f*W[k*100+o] : 0.f;
    Wt[r] = __float2bfloat16(v);
  }
}

// ---------------------------------------------------------------------------
// Fused radial + GEMM + TP + atomic scatter-add. LDS 54016 B -> 3 blocks/CU.
// Phase loop is __syncthreads-FREE (all state wave-local; A-fragments and C3
// read from global).
// ---------------------------------------------------------------------------
constexpr int OF_RT  = 0;         // 64*68 f32 = 17408
constexpr int OF_ACC = 17408;     // 64*40 f32 = 10240 (live LO-group slice)
constexpr int OF_F   = 27648;     // 64*76 f32 = 19456
constexpr int OF_KV  = 47104;     // 64*25 f32 = 6400
constexpr int OF_SRC = 53504;     // 64 int = 256
constexpr int OF_TGT = 53760;     // 64 int = 256
constexpr int SMEM_SZ = 54016;    // 3 x 54272(rounded) = 162816 <= 163840

// radial overlay (prologue only; fused buffers dead then)
constexpr int OF_BAS  = 0;        // 640 f32 = 2560
constexpr int OF_HA   = 2560;     // 64*136 bf16 = 17408
constexpr int OF_HB   = 19968;    // 64*136 bf16 = 17408 -> ends 37376

__device__ __forceinline__ float swishf(float s){
  return SWISH_SCALE * s / (1.f + __expf(-s));
}

// radial MFMA layer, A-fragments coalesced from global (fragment-contiguous)
__device__ __forceinline__ void radial_layer_glb(
    const __hip_bfloat16* __restrict__ sIn,   // [64][136] bf16 LDS, rows e
    const __hip_bfloat16* __restrict__ Wt,    // global, fragment-permuted
    __hip_bfloat16* __restrict__ sOut,        // [64][136] bf16 LDS
    int lane, int wv, int lr, int lq)
{
  bf16x8 bf[4];
  #pragma unroll
  for (int ks=0; ks<4; ++ks)
    bf[ks] = *(const bf16x8*)&sIn[(wv*16+lr)*136 + ks*32 + lq*8];
  f32x4 acc[7] = {};
  #pragma unroll
  for (int ks=0; ks<4; ++ks)
    #pragma unroll
    for (int ot=0; ot<7; ++ot){
      bf16x8 a = *(const bf16x8*)&Wt[((ot*4+ks)*64 + lane)*8];
      acc[ot] = __builtin_amdgcn_mfma_f32_16x16x32_bf16(a, bf[ks], acc[ot], 0, 0, 0);
    }
  // C frag: col(lr)=e within wave, row(ot*16+lq*4+r)=o.  swish + bf16 + short4.
  #pragma unroll
  for (int ot=0; ot<7; ++ot){
    __hip_bfloat16 hv[4];
    #pragma unroll
    for (int r=0; r<4; ++r)
      hv[r] = __float2bfloat16(swishf(acc[ot][r]));   // Wt rows o>=100 zero -> swish(0)=0
    *(short4*)&sOut[(wv*16+lr)*136 + ot*16 + lq*4] = *(short4*)hv;
  }
  // zero k = 112..127 of own rows COMPLETELY: 64 lanes = 16 rows x 4 quarters
  {
    int l2 = lq*16 + lr;              // 0..63
    int row = l2 & 15, q = l2 >> 4;   // q in 0..3
    short4 z = {0,0,0,0};
    *(short4*)&sOut[(wv*16+row)*136 + 112 + q*4] = z;
  }
}

template<int LO,int LI,int LF>
__device__ __forceinline__ void kv_sec(float* kvb, const float* __restrict__ C3g,
                                       const float* __restrict__ rshrow,
                                       int e, int role)
{
  constexpr int NO = 2*LO+1, NI = 2*LI+1, NF = 2*LF+1;
  constexpr int C3B = C3OFFT[LO][LI][LF];
  float y[NF];
  #pragma unroll
  for (int mf=0; mf<NF; ++mf) y[mf] = rshrow[LF*LF + mf];
  for (int it = role; it < NO*NI; it += 4){
    float s = 0.f;
    #pragma unroll
    for (int mf=0; mf<NF; ++mf) s += C3g[C3B + it*NF + mf] * y[mf];
    kvb[e*25 + it] = s;
  }
}

template<int LO,int LI>
__device__ __forceinline__ void consume_sec(
    const float* sRt, const float* sFf, const float* kvb, float* sAcc,
    int e, int role)
{
  constexpr int NO = 2*LO+1, NI = 2*LI+1;
  constexpr int FO = FOFFT[LI];
  float H[2][NI];
  #pragma unroll
  for (int du=0; du<2; ++du)
    #pragma unroll
    for (int mi=0; mi<NI; ++mi) H[du][mi] = 0.f;

  #pragma unroll
  for (int vg=0; vg<2; ++vg){
    float fb[4*NI];
    #pragma unroll
    for (int p=0; p<NI; ++p)
      *(f32x4*)&fb[p*4] = *(const f32x4*)&sFf[e*76 + FO + vg*4*NI + p*4];
    #pragma unroll
    for (int du=0; du<2; ++du){
      const int u = role*2 + du;
      f32x4 rv = *(const f32x4*)&sRt[e*68 + u*8 + vg*4];
      #pragma unroll
      for (int v=0; v<4; ++v)
        #pragma unroll
        for (int mi=0; mi<NI; ++mi)
          H[du][mi] += rv[v] * fb[v*NI + mi];
    }
  }
  // accumulate into group-local LDS slice (pitch 40):
  // LO=0: col=u (0..7); LO=1: col=u*3+o (0..23); LO=2: col=u*5+o (0..39)
  const int u0 = role*2, u1 = role*2 + 1;
  const int b0 = e*40 + ((LO==0) ? u0 : (LO==1) ? u0*3 : u0*5);
  const int b1 = e*40 + ((LO==0) ? u1 : (LO==1) ? u1*3 : u1*5);
  #pragma unroll
  for (int o=0; o<NO; ++o){
    float s0 = 0.f, s1 = 0.f;
    #pragma unroll
    for (int mi=0; mi<NI; ++mi){
      float kvv = kvb[e*25 + o*NI + mi];
      s0 += kvv * H[0][mi];
      s1 += kvv * H[1][mi];
    }
    sAcc[b0 + o] += s0;
    sAcc[b1 + o] += s1;
  }
}

// wave-local MFMA, A-fragments coalesced from global (fragment-contiguous)
__device__ __forceinline__ void mfma_sec_glb(
    const __hip_bfloat16* __restrict__ gW,    // W3t + chunk*8192
    float* sRt, const bf16x8 (&hf)[4],
    int lane, int wv, int lr, int lq)
{
  f32x4 a4[4] = {};
  #pragma unroll
  for (int ks=0; ks<4; ++ks){
    #pragma unroll
    for (int ct=0; ct<4; ++ct){
      bf16x8 a = *(const bf16x8*)&gW[((ct*4+ks)*64 + lane)*8];
      a4[ct] = __builtin_amdgcn_mfma_f32_16x16x32_bf16(a, hf[ks], a4[ct], 0, 0, 0);
    }
  }
  #pragma unroll
  for (int ct=0; ct<4; ++ct)
    *(f32x4*)&sRt[(wv*16 + lr)*68 + ct*16 + lq*4] = a4[ct];
}

// Wave-local flush: atomic scatter-add of the LO-group slice into out.
template<int J0,int W>
__device__ __forceinline__ void flush_group(float* sAcc, float* __restrict__ out,
                                            const int* sTgt, int eb, int t,
                                            float nrm, int E)
{
  const int lane = t & 63, wv = t >> 6;
  __builtin_amdgcn_wave_barrier();
  for (int p = lane; p < 16*W; p += 64){
    int el = wv*16 + p/W, j = p%W;
    if (eb + el < E)
      atomicAdd(&out[(size_t)sTgt[el]*FEATD + J0 + j], nrm * sAcc[el*40 + j]);
    sAcc[el*40 + j] = 0.f;                 // ready for next group
  }
  __builtin_amdgcn_wave_barrier();
}

// One phase, fully wave-local, NO block barriers:
// kv -> MFMA(global frags) -> wave_barrier -> consume -> wave_barrier.
template<int LO,int LI,int LF>
__device__ __forceinline__ void phase(
    int chunk, const __hip_bfloat16* __restrict__ W3t, const bf16x8 (&hf)[4],
    float* sRt, float* sFf, float* sKV, const float* __restrict__ C3g,
    const float* __restrict__ rshrow, float* sAcc, int t)
{
  const int e = t >> 2, role = t & 3;
  const int lane = t & 63, wv = t >> 6;
  const int lr = lane & 15, lq = lane >> 4;

  kv_sec<LO,LI,LF>(sKV, C3g, rshrow, e, role);
  mfma_sec_glb(W3t + (size_t)chunk*8192, sRt, hf, lane, wv, lr, lq);
  __builtin_amdgcn_wave_barrier();
  consume_sec<LO,LI>(sRt, sFf, sKV, sAcc, e, role);
  __builtin_amdgcn_wave_barrier();
}

__global__ __launch_bounds__(256,3) void fused_kernel(
    const float* __restrict__ feats, const int* __restrict__ ei,
    const float* __restrict__ radii, const float* __restrict__ rsh,
    const float* __restrict__ W0,
    const __hip_bfloat16* __restrict__ W1t, const __hip_bfloat16* __restrict__ W2t,
    const __hip_bfloat16* __restrict__ W3t, const float* __restrict__ C3g,
    float* __restrict__ out, int E)
{
  __shared__ __align__(16) char smem[SMEM_SZ];
  // fused-view pointers
  float* sRt  = (float*)(smem + OF_RT);
  float* sAcc = (float*)(smem + OF_ACC);
  float* sFf  = (float*)(smem + OF_F);
  float* sKV  = (float*)(smem + OF_KV);
  int*   sSrc = (int*)(smem + OF_SRC);
  int*   sTgt = (int*)(smem + OF_TGT);
  // radial-overlay pointers (prologue only)
  float* sbas = (float*)(smem + OF_BAS);
  __hip_bfloat16* hA = (__hip_bfloat16*)(smem + OF_HA);
  __hip_bfloat16* hB = (__hip_bfloat16*)(smem + OF_HB);

  const int t = threadIdx.x;
  const int eb = blockIdx.x*64;
  const int lane = t & 63, wv = t >> 6;
  const int lr = lane & 15, lq = lane >> 4;

  // ===================== radial prologue (barrier-light) ===================
  for (int p=t; p<640; p+=256){
    int er = p/10, k = p%10;
    int eg = eb + er;
    float r = (eg < E) ? radii[eg] : 0.f;
    float c = 0.7f + (2.5f/9.0f)*(float)k;
    float d = (r - c) * (9.0f/2.5f);
    sbas[p] = __expf(-d*d);
  }
  __syncthreads();
  // layer 1 (K=10, VALU), h1 bf16 into hA; zero k-pad 100..135
  for (int p=t; p<6400; p+=256){
    int er = p/100, o = p%100;
    float s = 0.f;
    #pragma unroll
    for (int k=0;k<10;++k) s += sbas[er*10+k]*W0[k*100+o];
    hA[er*136+o] = __float2bfloat16(swishf(s*0.3162277660168379f));   // 1/sqrt(10)
  }
  for (int p=t; p<64*36; p+=256){
    int er = p/36, k = 100 + p%36;
    hA[er*136+k] = __float2bfloat16(0.f);
  }
  __syncthreads();   // hA (cross-wave writes) ready

  radial_layer_glb(hA, W1t, hB, lane, wv, lr, lq);   // h2 (own rows)
  __builtin_amdgcn_wave_barrier();
  radial_layer_glb(hB, W2t, hA, lane, wv, lr, lq);   // h3 (own rows)
  __builtin_amdgcn_wave_barrier();

  // B-fragments straight from LDS (own wave rows)
  bf16x8 hf[4];
  #pragma unroll
  for (int ks=0; ks<4; ++ks)
    hf[ks] = *(const bf16x8*)&hA[(wv*16+lr)*136 + ks*32 + lq*8];

  __syncthreads();   // radial overlay dead; fused buffers may now be written

  // ===================== fused init ========================================
  for (int p=t; p<2560; p+=256) sAcc[p] = 0.f;
  for (int p=t; p<64; p+=256){
    int e = eb + p;
    sSrc[p] = (e < E) ? ei[e] : 0;
    sTgt[p] = (e < E) ? ei[E + e] : 0;
  }
  __syncthreads();
  for (int p=t; p<64*72; p+=256){
    int el = p/72, j = p%72;
    sFf[el*76 + j] = feats[(size_t)sSrc[el]*72 + j];
  }
  __syncthreads();   // LAST block barrier — phase loop below is barrier-free

  // own-edge rsh row, pad-clamped (pad rows never flushed: eg<E guard)
  int eg = eb + (t >> 2); if (eg > E-1) eg = E-1;
  const float* rshrow = rsh + (size_t)eg*25;

  // ---- group LO=0: output cols 0..7 ----
  phase<0,0,0>( 0, W3t, hf, sRt, sFf, sKV, C3g, rshrow, sAcc, t);
  phase<0,1,1>( 1, W3t, hf, sRt, sFf, sKV, C3g, rshrow, sAcc, t);
  phase<0,2,2>( 2, W3t, hf, sRt, sFf, sKV, C3g, rshrow, sAcc, t);
  flush_group<0,8>(sAcc, out, sTgt, eb, t, 0.72360125f, E);

  // ---- group LO=1: output cols 8..31 ----
  phase<1,0,1>( 3, W3t, hf, sRt, sFf, sKV, C3g, rshrow, sAcc, t);
  phase<1,1,0>( 4, W3t, hf, sRt, sFf, sKV, C3g, rshrow, sAcc, t);
  phase<1,1,1>( 5, W3t, hf, sRt, sFf, sKV, C3g, rshrow, sAcc, t);
  phase<1,1,2>( 6, W3t, hf, sRt, sFf, sKV, C3g, rshrow, sAcc, t);
  phase<1,2,1>( 7, W3t, hf, sRt, sFf, sKV, C3g, rshrow, sAcc, t);
  phase<1,2,2>( 8, W3t, hf, sRt, sFf, sKV, C3g, rshrow, sAcc, t);
  phase<1,2,3>( 9, W3t, hf, sRt, sFf, sKV, C3g, rshrow, sAcc, t);
  flush_group<8,24>(sAcc, out, sTgt, eb, t, 0.8204867f, E);

  // ---- group LO=2: output cols 32..71 ----
  phase<2,0,2>(10, W3t, hf, sRt, sFf, sKV, C3g, rshrow, sAcc, t);
  phase<2,1,1>(11, W3t, hf, sRt, sFf, sKV, C3g, rshrow, sAcc, t);
  phase<2,1,2>(12, W3t, hf, sRt, sFf, sKV, C3g, rshrow, sAcc, t);
  phase<2,1,3>(13, W3t, hf, sRt, sFf, sKV, C3g, rshrow, sAcc, t);
  phase<2,2,0>(14, W3t, hf, sRt, sFf, sKV, C3g, rshrow, sAcc, t);
  phase<2,2,1>(15, W3t, hf, sRt, sFf, sKV, C3g, rshrow, sAcc, t);
  phase<2,2,2>(16, W3t, hf, sRt, sFf, sKV, C3g, rshrow, sAcc, t);
  phase<2,2,3>(17, W3t, hf, sRt, sFf, sKV, C3g, rshrow, sAcc, t);
  phase<2,2,4>(18, W3t, hf, sRt, sFf, sKV, C3g, rshrow, sAcc, t);
  flush_group<32,40>(sAcc, out, sTgt, eb, t, 0.9341652f, E);
}

// ---------------------------------------------------------------------------
extern "C" void kernel_launch(void* const* d_in, const int* in_sizes, int n_in,
                              void* d_out, int out_size, void* d_ws, size_t ws_size,
                              hipStream_t stream)
{
  const float* feats = (const float*)d_in[0];
  const int*   ei    = (const int*)d_in[1];
  const float* radii = (const float*)d_in[2];
  const float* rsh   = (const float*)d_in[3];
  const float* W0    = (const float*)d_in[4];
  const float* W1    = (const float*)d_in[5];
  const float* W2    = (const float*)d_in[6];
  const float* W3    = (const float*)d_in[7];
  float* out = (float*)d_out;
  const int E = in_sizes[2];

  const int EPAD = ((E + 63)/64)*64;
  const int NBLK = EPAD/64;

  char* ws = (char*)d_ws;
  size_t off_b = 0;
  float*  C3f = (float*)(ws + off_b);  off_b += 8192;
  __hip_bfloat16* W3t = (__hip_bfloat16*)(ws + off_b); off_b += 335872;  // 19*16KB used
  __hip_bfloat16* W1t = (__hip_bfloat16*)(ws + off_b); off_b += 30720;   // 14336 elems used
  __hip_bfloat16* W2t = (__hip_bfloat16*)(ws + off_b); off_b += 30720;

  // out accumulates via atomics -> zero it inside the graph
  hipMemsetAsync(out, 0, (size_t)out_size*sizeof(float), stream);

  // merged constants/tables: 19 c3 blocks + 720 repack blocks
  constexpr int PREP_BLKS = (19*8192 + 2*14336 + 255)/256;   // 720
  init_kernel<<<dim3(NCOMBO + PREP_BLKS), dim3(256), 0, stream>>>(
      W3, W1, W2, W3t, W1t, W2t, C3f);

  // main pipeline: fused radial + GEMM + TP + atomic scatter-add
  fused_kernel<<<dim3(NBLK), dim3(256), 0, stream>>>(
      feats, ei, radii, rsh, W0, W1t, W2t, W3t, C3f, out, E);
}

// Round 12
// 337.616 us; speedup vs baseline: 1.0792x; 1.0792x over previous
//
#include <hip/hip_runtime.h>
#include <hip/hip_bf16.h>
#include <math.h>

// ============================================================================
// MinimalNetwork, round 26: best-pieces recombination + critical-path trims.
// r25 post-mortem: C3-from-global regressed (212->229) and occupancy DIDN'T
// rise at 3-blk/CU LDS fit -> occupancy is a dead lever (3rd refutation).
// This round: r24 fused (barrier-free, frag-contiguous, C3 in LDS, (256,2))
// + r25 merged init_kernel, plus:
//   - rsh edge-row preloaded into 25 registers (static idx: LF*LF+mf all
//     constexpr/unrolled) -> kv loses its per-phase global loads.
//   - s_setprio(1) around MFMA (T5): prerequisite "waves at different
//     phases" is finally met by the barrier-free loop.
// Kill: total>=355 -> declare structural/measurement floor next round.
// ============================================================================

#define FEATD 72
#define NCOL 1216
#define SWISH_SCALE 1.679177f

typedef __attribute__((ext_vector_type(8))) short bf16x8;
typedef __attribute__((ext_vector_type(4))) float f32x4;

// ---- 19 (lo,li,lf) chunks; CB_OFF = offsets into the C3 coefficient pool ----
constexpr int NCOMBO = 19;
constexpr int CB_LO[NCOMBO] = {0,0,0,1,1,1,1,1,1,1,2,2,2,2,2,2,2,2,2};
constexpr int CB_LI[NCOMBO] = {0,1,2,0,1,1,1,2,2,2,0,1,1,1,2,2,2,2,2};
constexpr int CB_LF[NCOMBO] = {0,1,2,1,0,1,2,1,2,3,2,1,2,3,0,1,2,3,4};
constexpr int CB_OFF[NCOMBO] = {0,1,10,35,44,53,80,125,170,245,350,375,420,495,600,625,700,825,1000};
constexpr int CB_SZ[NCOMBO]  = {1,9,25,9,9,27,45,45,75,105,25,45,75,105,25,75,125,175,225};
constexpr int C3TOT = 1225;

constexpr int C3OFFT[3][3][5] = {
  { {0,-1,-1,-1,-1}, {-1,1,-1,-1,-1}, {-1,-1,10,-1,-1} },
  { {-1,35,-1,-1,-1}, {44,53,80,-1,-1}, {-1,125,170,245,-1} },
  { {-1,-1,350,-1,-1}, {-1,375,420,495,-1}, {600,625,700,825,1000} }
};
constexpr int ROFFT[3][3] = {{0,64,128},{192,256,448},{640,704,896}};
constexpr int FOFFT[3]   = {0,8,32};

__device__ const double d_fact[11] = {1.,1.,2.,6.,24.,120.,720.,5040.,40320.,362880.,3628800.};

// ---------------------------------------------------------------------------
// Wigner 3j (complex basis, Racah) in double precision + real change of basis
// ---------------------------------------------------------------------------
__device__ double w3j_entry(int j1,int j2,int j3,int m1,int m2,int m3){
  if (m1+m2+m3 != 0) return 0.0;
  int dj = j1-j2; if (dj<0) dj=-dj;
  if (j3 < dj || j3 > j1+j2) return 0.0;
  int t1 = j2 - m1 - j3, t2 = j1 + m2 - j3;
  int kmin = 0; if (t1>kmin) kmin=t1; if (t2>kmin) kmin=t2;
  int kmax = j1+j2-j3; if (j1-m1<kmax) kmax=j1-m1; if (j2+m2<kmax) kmax=j2+m2;
  double s = 0.0;
  for (int k=kmin;k<=kmax;++k){
    double den = d_fact[k]*d_fact[k-t1]*d_fact[k-t2]*d_fact[j1+j2-j3-k]
               * d_fact[j1-m1-k]*d_fact[j2+m2-k];
    s += ((k&1)? -1.0:1.0)/den;
  }
  double pref = sqrt(d_fact[j1+j2-j3]*d_fact[j1-j2+j3]*d_fact[-j1+j2+j3]/d_fact[j1+j2+j3+1]
               * d_fact[j1+m1]*d_fact[j1-m1]*d_fact[j2+m2]*d_fact[j2-m2]
               * d_fact[j3+m3]*d_fact[j3-m3]);
  int ex = j1-j2-m3;
  if (ex & 1) pref = -pref;
  return pref*s;
}

__device__ void cob(int l, int r, int c, double& re, double& im){
  re = 0.0; im = 0.0;
  int mr = r - l, mc = c - l;
  const double s = 0.70710678118654752440;
  if (mr == 0) { if (mc == 0) re = 1.0; return; }
  if (mr > 0) {
    if (mc == mr)       re = (mr & 1) ? -s : s;
    else if (mc == -mr) re = s;
  } else {
    int m = -mr;
    if (mc == -m)      im = s;
    else if (mc == m)  im = (m & 1) ? s : -s;
  }
}

// ---------------------------------------------------------------------------
// Merged init: blocks 0..18 build+normalize one C3 chunk (wave 0 active);
// blocks 19.. repack W3t/W1t/W2t into the fragment-contiguous layout:
//   W3t elem idx = chunk*8192 + ((ct*4+ks)*64 + lane)*8 + j
//     encodes row r = ct*16+(lane&15), k = ks*32+(lane>>4)*8+j.
//   W1t/W2t elem idx = ((ot*4+ks)*64 + lane)*8 + j  (ot=0..6).
// 0.1 scale folded; k>=100 / o>=100 zero-padded.
// ---------------------------------------------------------------------------
__global__ __launch_bounds__(256) void init_kernel(
    const float* __restrict__ W3, const float* __restrict__ W1,
    const float* __restrict__ W2, __hip_bfloat16* __restrict__ W3t,
    __hip_bfloat16* __restrict__ W1t, __hip_bfloat16* __restrict__ W2t,
    float* __restrict__ C3f)
{
  if (blockIdx.x < NCOMBO){
    __shared__ double sre[225], sim[225];
    const int c = blockIdx.x;
    const int lo = CB_LO[c], li = CB_LI[c], lf = CB_LF[c];
    const int off = CB_OFF[c], sz = CB_SZ[c];
    const int n2 = 2*li+1, n3 = 2*lf+1;
    const int t = threadIdx.x;

    if (t < 64){
      for (int p=t; p<sz; p+=64){
        int a = p/(n2*n3), b = (p/n3)%n2, g = p%n3;
        double re=0.0, im=0.0;
        for (int m1=-lo; m1<=lo; ++m1){
          for (int m2=-li; m2<=li; ++m2){
            int m3 = -m1-m2;
            if (m3 < -lf || m3 > lf) continue;
            double w = w3j_entry(lo,li,lf,m1,m2,m3);
            if (w == 0.0) continue;
            double r1,i1,r2,i2,r3,i3;
            cob(lo, a, m1+lo, r1,i1);
            cob(li, b, m2+li, r2,i2);
            cob(lf, g, m3+lf, r3,i3);
            double rr = r1*r2 - i1*i2, ri = r1*i2 + i1*r2;
            double fr = rr*r3 - ri*i3, fi = rr*i3 + ri*r3;
            re += fr*w; im += fi*w;
          }
        }
        sre[p] = re; sim[p] = im;
      }
    }
    __syncthreads();
    if (t < 64){
      double s2r=0.0, s2i=0.0;
      for (int p=t; p<sz; p+=64){ double x=sre[p], y=sim[p]; s2r+=x*x; s2i+=y*y; }
      for (int m=1; m<64; m<<=1){ s2r += __shfl_xor(s2r, m, 64); s2i += __shfl_xor(s2i, m, 64); }
      bool useRe = (s2r >= s2i);
      double n = sqrt(useRe ? s2r : s2i);
      double inv = (n > 0.0) ? 1.0/n : 1.0;
      for (int p=t; p<sz; p+=64){
        double v = useRe ? sre[p] : sim[p];
        C3f[off+p] = (float)(v*inv);
      }
    }
    return;
  }

  int idx = (blockIdx.x - NCOMBO)*256 + threadIdx.x;
  constexpr int NW3 = 19*8192;       // 155648
  constexpr int HALF = 7*4*64*8;     // 14336
  if (idx < NW3){
    int j = idx & 7, lane = (idx>>3)&63, kc = (idx>>9)&15, chunk = idx>>13;
    int ks = kc & 3, ct = kc >> 2;
    int r = ct*16 + (lane&15);
    int k = ks*32 + (lane>>4)*8 + j;
    int lo = CB_LO[chunk], li = CB_LI[chunk], lf = CB_LF[chunk];
    int lmin = lo<li ? lo : li;
    int nlf = 2*lmin+1;
    int fi = lf - (lo>li ? lo-li : li-lo);
    int c = ROFFT[lo][li] + r*nlf + fi;
    float v = (k < 100) ? 0.1f*W3[(size_t)k*NCOL + c] : 0.f;
    W3t[idx] = __float2bfloat16(v);
  } else if (idx < NW3 + 2*HALF){
    int r2 = idx - NW3;
    const float* W = (r2 < HALF) ? W1 : W2;
    __hip_bfloat16* Wt = (r2 < HALF) ? W1t : W2t;
    int r = (r2 < HALF) ? r2 : r2 - HALF;
    int j = r & 7, lane = (r>>3)&63, kc = r>>9;   // kc = ot*4+ks in 0..27
    int ks = kc & 3, ot = kc >> 2;
    int o = ot*16 + (lane&15);
    int k = ks*32 + (lane>>4)*8 + j;
    float v = (o < 100 && k < 100) ? 0.1f*W[k*100+o] : 0.f;
    Wt[r] = __float2bfloat16(v);
  }
}

// ---------------------------------------------------------------------------
// Fused radial + GEMM + TP + atomic scatter-add. LDS 58916 B, 2 blocks/CU.
// Phase loop is __syncthreads-FREE (state wave-local; A-fragments global,
// C3 in LDS, rsh row in registers).
// ---------------------------------------------------------------------------
constexpr int OF_RT  = 0;         // 64*68 f32 = 17408
constexpr int OF_ACC = 17408;     // 64*40 f32 = 10240 (live LO-group slice)
constexpr int OF_F   = 27648;     // 64*76 f32 = 19456
constexpr int OF_KV  = 47104;     // 64*25 f32 = 6400
constexpr int OF_C3  = 53504;     // 1225 f32 = 4900
constexpr int OF_SRC = 58404;     // 64 int = 256
constexpr int OF_TGT = 58660;     // 64 int = 256
constexpr int SMEM_SZ = 58916;

// radial overlay (prologue only; fused buffers dead then)
constexpr int OF_BAS  = 0;        // 640 f32 = 2560
constexpr int OF_HA   = 2560;     // 64*136 bf16 = 17408
constexpr int OF_HB   = 19968;    // 64*136 bf16 = 17408 -> ends 37376

__device__ __forceinline__ float swishf(float s){
  return SWISH_SCALE * s / (1.f + __expf(-s));
}

// radial MFMA layer, A-fragments coalesced from global (fragment-contiguous)
__device__ __forceinline__ void radial_layer_glb(
    const __hip_bfloat16* __restrict__ sIn,   // [64][136] bf16 LDS, rows e
    const __hip_bfloat16* __restrict__ Wt,    // global, fragment-permuted
    __hip_bfloat16* __restrict__ sOut,        // [64][136] bf16 LDS
    int lane, int wv, int lr, int lq)
{
  bf16x8 bf[4];
  #pragma unroll
  for (int ks=0; ks<4; ++ks)
    bf[ks] = *(const bf16x8*)&sIn[(wv*16+lr)*136 + ks*32 + lq*8];
  f32x4 acc[7] = {};
  #pragma unroll
  for (int ks=0; ks<4; ++ks)
    #pragma unroll
    for (int ot=0; ot<7; ++ot){
      bf16x8 a = *(const bf16x8*)&Wt[((ot*4+ks)*64 + lane)*8];
      acc[ot] = __builtin_amdgcn_mfma_f32_16x16x32_bf16(a, bf[ks], acc[ot], 0, 0, 0);
    }
  // C frag: col(lr)=e within wave, row(ot*16+lq*4+r)=o.  swish + bf16 + short4.
  #pragma unroll
  for (int ot=0; ot<7; ++ot){
    __hip_bfloat16 hv[4];
    #pragma unroll
    for (int r=0; r<4; ++r)
      hv[r] = __float2bfloat16(swishf(acc[ot][r]));   // Wt rows o>=100 zero -> swish(0)=0
    *(short4*)&sOut[(wv*16+lr)*136 + ot*16 + lq*4] = *(short4*)hv;
  }
  // zero k = 112..127 of own rows COMPLETELY: 64 lanes = 16 rows x 4 quarters
  {
    int l2 = lq*16 + lr;              // 0..63
    int row = l2 & 15, q = l2 >> 4;   // q in 0..3
    short4 z = {0,0,0,0};
    *(short4*)&sOut[(wv*16+row)*136 + 112 + q*4] = z;
  }
}

template<int LO,int LI,int LF>
__device__ __forceinline__ void kv_sec(float* kvb, const float* sC3,
                                       const float (&rr)[25],
                                       int e, int role)
{
  constexpr int NO = 2*LO+1, NI = 2*LI+1, NF = 2*LF+1;
  constexpr int C3B = C3OFFT[LO][LI][LF];
  for (int it = role; it < NO*NI; it += 4){
    float s = 0.f;
    #pragma unroll
    for (int mf=0; mf<NF; ++mf) s += sC3[C3B + it*NF + mf] * rr[LF*LF + mf];
    kvb[e*25 + it] = s;
  }
}

template<int LO,int LI>
__device__ __forceinline__ void consume_sec(
    const float* sRt, const float* sFf, const float* kvb, float* sAcc,
    int e, int role)
{
  constexpr int NO = 2*LO+1, NI = 2*LI+1;
  constexpr int FO = FOFFT[LI];
  float H[2][NI];
  #pragma unroll
  for (int du=0; du<2; ++du)
    #pragma unroll
    for (int mi=0; mi<NI; ++mi) H[du][mi] = 0.f;

  #pragma unroll
  for (int vg=0; vg<2; ++vg){
    float fb[4*NI];
    #pragma unroll
    for (int p=0; p<NI; ++p)
      *(f32x4*)&fb[p*4] = *(const f32x4*)&sFf[e*76 + FO + vg*4*NI + p*4];
    #pragma unroll
    for (int du=0; du<2; ++du){
      const int u = role*2 + du;
      f32x4 rv = *(const f32x4*)&sRt[e*68 + u*8 + vg*4];
      #pragma unroll
      for (int v=0; v<4; ++v)
        #pragma unroll
        for (int mi=0; mi<NI; ++mi)
          H[du][mi] += rv[v] * fb[v*NI + mi];
    }
  }
  // accumulate into group-local LDS slice (pitch 40):
  // LO=0: col=u (0..7); LO=1: col=u*3+o (0..23); LO=2: col=u*5+o (0..39)
  const int u0 = role*2, u1 = role*2 + 1;
  const int b0 = e*40 + ((LO==0) ? u0 : (LO==1) ? u0*3 : u0*5);
  const int b1 = e*40 + ((LO==0) ? u1 : (LO==1) ? u1*3 : u1*5);
  #pragma unroll
  for (int o=0; o<NO; ++o){
    float s0 = 0.f, s1 = 0.f;
    #pragma unroll
    for (int mi=0; mi<NI; ++mi){
      float kvv = kvb[e*25 + o*NI + mi];
      s0 += kvv * H[0][mi];
      s1 += kvv * H[1][mi];
    }
    sAcc[b0 + o] += s0;
    sAcc[b1 + o] += s1;
  }
}

// wave-local MFMA, A-fragments coalesced from global; setprio'd (T5: waves
// drift through the barrier-free loop -> scheduler has roles to arbitrate).
__device__ __forceinline__ void mfma_sec_glb(
    const __hip_bfloat16* __restrict__ gW,    // W3t + chunk*8192
    float* sRt, const bf16x8 (&hf)[4],
    int lane, int wv, int lr, int lq)
{
  f32x4 a4[4] = {};
  __builtin_amdgcn_s_setprio(1);
  #pragma unroll
  for (int ks=0; ks<4; ++ks){
    #pragma unroll
    for (int ct=0; ct<4; ++ct){
      bf16x8 a = *(const bf16x8*)&gW[((ct*4+ks)*64 + lane)*8];
      a4[ct] = __builtin_amdgcn_mfma_f32_16x16x32_bf16(a, hf[ks], a4[ct], 0, 0, 0);
    }
  }
  __builtin_amdgcn_s_setprio(0);
  #pragma unroll
  for (int ct=0; ct<4; ++ct)
    *(f32x4*)&sRt[(wv*16 + lr)*68 + ct*16 + lq*4] = a4[ct];
}

// Wave-local flush: atomic scatter-add of the LO-group slice into out.
template<int J0,int W>
__device__ __forceinline__ void flush_group(float* sAcc, float* __restrict__ out,
                                            const int* sTgt, int eb, int t,
                                            float nrm, int E)
{
  const int lane = t & 63, wv = t >> 6;
  __builtin_amdgcn_wave_barrier();
  for (int p = lane; p < 16*W; p += 64){
    int el = wv*16 + p/W, j = p%W;
    if (eb + el < E)
      atomicAdd(&out[(size_t)sTgt[el]*FEATD + J0 + j], nrm * sAcc[el*40 + j]);
    sAcc[el*40 + j] = 0.f;                 // ready for next group
  }
  __builtin_amdgcn_wave_barrier();
}

// One phase, fully wave-local, NO block barriers:
// kv -> MFMA(global frags) -> wave_barrier -> consume -> wave_barrier.
template<int LO,int LI,int LF>
__device__ __forceinline__ void phase(
    int chunk, const __hip_bfloat16* __restrict__ W3t, const bf16x8 (&hf)[4],
    float* sRt, float* sFf, float* sKV, const float* sC3,
    const float (&rr)[25], float* sAcc, int t)
{
  const int e = t >> 2, role = t & 3;
  const int lane = t & 63, wv = t >> 6;
  const int lr = lane & 15, lq = lane >> 4;

  kv_sec<LO,LI,LF>(sKV, sC3, rr, e, role);
  mfma_sec_glb(W3t + (size_t)chunk*8192, sRt, hf, lane, wv, lr, lq);
  __builtin_amdgcn_wave_barrier();
  consume_sec<LO,LI>(sRt, sFf, sKV, sAcc, e, role);
  __builtin_amdgcn_wave_barrier();
}

__global__ __launch_bounds__(256,2) void fused_kernel(
    const float* __restrict__ feats, const int* __restrict__ ei,
    const float* __restrict__ radii, const float* __restrict__ rsh,
    const float* __restrict__ W0,
    const __hip_bfloat16* __restrict__ W1t, const __hip_bfloat16* __restrict__ W2t,
    const __hip_bfloat16* __restrict__ W3t, const float* __restrict__ C3g,
    float* __restrict__ out, int E)
{
  __shared__ __align__(16) char smem[SMEM_SZ];
  // fused-view pointers
  float* sRt  = (float*)(smem + OF_RT);
  float* sAcc = (float*)(smem + OF_ACC);
  float* sFf  = (float*)(smem + OF_F);
  float* sKV  = (float*)(smem + OF_KV);
  float* sC3  = (float*)(smem + OF_C3);
  int*   sSrc = (int*)(smem + OF_SRC);
  int*   sTgt = (int*)(smem + OF_TGT);
  // radial-overlay pointers (prologue only)
  float* sbas = (float*)(smem + OF_BAS);
  __hip_bfloat16* hA = (__hip_bfloat16*)(smem + OF_HA);
  __hip_bfloat16* hB = (__hip_bfloat16*)(smem + OF_HB);

  const int t = threadIdx.x;
  const int eb = blockIdx.x*64;
  const int lane = t & 63, wv = t >> 6;
  const int lr = lane & 15, lq = lane >> 4;

  // ===================== radial prologue (barrier-light) ===================
  for (int p=t; p<640; p+=256){
    int er = p/10, k = p%10;
    int eg = eb + er;
    float r = (eg < E) ? radii[eg] : 0.f;
    float c = 0.7f + (2.5f/9.0f)*(float)k;
    float d = (r - c) * (9.0f/2.5f);
    sbas[p] = __expf(-d*d);
  }
  __syncthreads();
  // layer 1 (K=10, VALU), h1 bf16 into hA; zero k-pad 100..135
  for (int p=t; p<6400; p+=256){
    int er = p/100, o = p%100;
    float s = 0.f;
    #pragma unroll
    for (int k=0;k<10;++k) s += sbas[er*10+k]*W0[k*100+o];
    hA[er*136+o] = __float2bfloat16(swishf(s*0.3162277660168379f));   // 1/sqrt(10)
  }
  for (int p=t; p<64*36; p+=256){
    int er = p/36, k = 100 + p%36;
    hA[er*136+k] = __float2bfloat16(0.f);
  }
  __syncthreads();   // hA (cross-wave writes) ready

  radial_layer_glb(hA, W1t, hB, lane, wv, lr, lq);   // h2 (own rows)
  __builtin_amdgcn_wave_barrier();
  radial_layer_glb(hB, W2t, hA, lane, wv, lr, lq);   // h3 (own rows)
  __builtin_amdgcn_wave_barrier();

  // B-fragments straight from LDS (own wave rows)
  bf16x8 hf[4];
  #pragma unroll
  for (int ks=0; ks<4; ++ks)
    hf[ks] = *(const bf16x8*)&hA[(wv*16+lr)*136 + ks*32 + lq*8];

  __syncthreads();   // radial overlay dead; fused buffers may now be written

  // ===================== fused init ========================================
  for (int p=t; p<2560; p+=256) sAcc[p] = 0.f;
  for (int p=t; p<64; p+=256){
    int e = eb + p;
    sSrc[p] = (e < E) ? ei[e] : 0;
    sTgt[p] = (e < E) ? ei[E + e] : 0;
  }
  for (int p=t; p<C3TOT; p+=256) sC3[p] = C3g[p];
  __syncthreads();
  for (int p=t; p<64*72; p+=256){
    int el = p/72, j = p%72;
    sFf[el*76 + j] = feats[(size_t)sSrc[el]*72 + j];
  }
  __syncthreads();   // LAST block barrier — phase loop below is barrier-free

  // own-edge rsh row -> 25 registers (static indexing only; pad-clamped)
  int eg = eb + (t >> 2); if (eg > E-1) eg = E-1;
  const float* rshrow = rsh + (size_t)eg*25;
  float rr[25];
  #pragma unroll
  for (int mf=0; mf<25; ++mf) rr[mf] = rshrow[mf];

  // ---- group LO=0: output cols 0..7 ----
  phase<0,0,0>( 0, W3t, hf, sRt, sFf, sKV, sC3, rr, sAcc, t);
  phase<0,1,1>( 1, W3t, hf, sRt, sFf, sKV, sC3, rr, sAcc, t);
  phase<0,2,2>( 2, W3t, hf, sRt, sFf, sKV, sC3, rr, sAcc, t);
  flush_group<0,8>(sAcc, out, sTgt, eb, t, 0.72360125f, E);

  // ---- group LO=1: output cols 8..31 ----
  phase<1,0,1>( 3, W3t, hf, sRt, sFf, sKV, sC3, rr, sAcc, t);
  phase<1,1,0>( 4, W3t, hf, sRt, sFf, sKV, sC3, rr, sAcc, t);
  phase<1,1,1>( 5, W3t, hf, sRt, sFf, sKV, sC3, rr, sAcc, t);
  phase<1,1,2>( 6, W3t, hf, sRt, sFf, sKV, sC3, rr, sAcc, t);
  phase<1,2,1>( 7, W3t, hf, sRt, sFf, sKV, sC3, rr, sAcc, t);
  phase<1,2,2>( 8, W3t, hf, sRt, sFf, sKV, sC3, rr, sAcc, t);
  phase<1,2,3>( 9, W3t, hf, sRt, sFf, sKV, sC3, rr, sAcc, t);
  flush_group<8,24>(sAcc, out, sTgt, eb, t, 0.8204867f, E);

  // ---- group LO=2: output cols 32..71 ----
  phase<2,0,2>(10, W3t, hf, sRt, sFf, sKV, sC3, rr, sAcc, t);
  phase<2,1,1>(11, W3t, hf, sRt, sFf, sKV, sC3, rr, sAcc, t);
  phase<2,1,2>(12, W3t, hf, sRt, sFf, sKV, sC3, rr, sAcc, t);
  phase<2,1,3>(13, W3t, hf, sRt, sFf, sKV, sC3, rr, sAcc, t);
  phase<2,2,0>(14, W3t, hf, sRt, sFf, sKV, sC3, rr, sAcc, t);
  phase<2,2,1>(15, W3t, hf, sRt, sFf, sKV, sC3, rr, sAcc, t);
  phase<2,2,2>(16, W3t, hf, sRt, sFf, sKV, sC3, rr, sAcc, t);
  phase<2,2,3>(17, W3t, hf, sRt, sFf, sKV, sC3, rr, sAcc, t);
  phase<2,2,4>(18, W3t, hf, sRt, sFf, sKV, sC3, rr, sAcc, t);
  flush_group<32,40>(sAcc, out, sTgt, eb, t, 0.9341652f, E);
}

// ---------------------------------------------------------------------------
extern "C" void kernel_launch(void* const* d_in, const int* in_sizes, int n_in,
                              void* d_out, int out_size, void* d_ws, size_t ws_size,
                              hipStream_t stream)
{
  const float* feats = (const float*)d_in[0];
  const int*   ei    = (const int*)d_in[1];
  const float* radii = (const float*)d_in[2];
  const float* rsh   = (const float*)d_in[3];
  const float* W0    = (const float*)d_in[4];
  const float* W1    = (const float*)d_in[5];
  const float* W2    = (const float*)d_in[6];
  const float* W3    = (const float*)d_in[7];
  float* out = (float*)d_out;
  const int E = in_sizes[2];

  const int EPAD = ((E + 63)/64)*64;
  const int NBLK = EPAD/64;

  char* ws = (char*)d_ws;
  size_t off_b = 0;
  float*  C3f = (float*)(ws + off_b);  off_b += 8192;
  __hip_bfloat16* W3t = (__hip_bfloat16*)(ws + off_b); off_b += 335872;  // 19*16KB used
  __hip_bfloat16* W1t = (__hip_bfloat16*)(ws + off_b); off_b += 30720;   // 14336 elems used
  __hip_bfloat16* W2t = (__hip_bfloat16*)(ws + off_b); off_b += 30720;

  // out accumulates via atomics -> zero it inside the graph
  hipMemsetAsync(out, 0, (size_t)out_size*sizeof(float), stream);

  // merged constants/tables: 19 c3 blocks + 720 repack blocks
  constexpr int PREP_BLKS = (19*8192 + 2*14336 + 255)/256;   // 720
  init_kernel<<<dim3(NCOMBO + PREP_BLKS), dim3(256), 0, stream>>>(
      W3, W1, W2, W3t, W1t, W2t, C3f);

  // main pipeline: fused radial + GEMM + TP + atomic scatter-add
  fused_kernel<<<dim3(NBLK), dim3(256), 0, stream>>>(
      feats, ei, radii, rsh, W0, W1t, W2t, W3t, C3f, out, E);
}

// Round 13
// 336.717 us; speedup vs baseline: 1.0821x; 1.0027x over previous
//
#include <hip/hip_runtime.h>
#include <hip/hip_bf16.h>
#include <math.h>

// ============================================================================
// MinimalNetwork, round 27: hoist F-operand into registers.
// r26: total 337.6 (best), fused 206, conflicts 1.8M. Still latency-bound
// (VALU 31 / MFMA 7.4 / HBM 3). Largest remaining per-phase LDS term:
// consume's fb loads (2*NI b128/thread/phase, re-reading the SAME 72 floats
// of the thread's own edge every phase). Change:
//   - fv[72] per-thread register copy of own F row, loaded once after the
//     gather (18 b128); consume indexes with fully-constexpr offsets.
//   - VGPR ~88->~170 (fine at 2 waves/SIMD); spill tripwire = WRITE_SIZE.
// Everything else identical to r26 (passing).
// Kill: WRITE_SIZE jump -> spill, revert; total>=340 -> declare floor.
// ============================================================================

#define FEATD 72
#define NCOL 1216
#define SWISH_SCALE 1.679177f

typedef __attribute__((ext_vector_type(8))) short bf16x8;
typedef __attribute__((ext_vector_type(4))) float f32x4;

// ---- 19 (lo,li,lf) chunks; CB_OFF = offsets into the C3 coefficient pool ----
constexpr int NCOMBO = 19;
constexpr int CB_LO[NCOMBO] = {0,0,0,1,1,1,1,1,1,1,2,2,2,2,2,2,2,2,2};
constexpr int CB_LI[NCOMBO] = {0,1,2,0,1,1,1,2,2,2,0,1,1,1,2,2,2,2,2};
constexpr int CB_LF[NCOMBO] = {0,1,2,1,0,1,2,1,2,3,2,1,2,3,0,1,2,3,4};
constexpr int CB_OFF[NCOMBO] = {0,1,10,35,44,53,80,125,170,245,350,375,420,495,600,625,700,825,1000};
constexpr int CB_SZ[NCOMBO]  = {1,9,25,9,9,27,45,45,75,105,25,45,75,105,25,75,125,175,225};
constexpr int C3TOT = 1225;

constexpr int C3OFFT[3][3][5] = {
  { {0,-1,-1,-1,-1}, {-1,1,-1,-1,-1}, {-1,-1,10,-1,-1} },
  { {-1,35,-1,-1,-1}, {44,53,80,-1,-1}, {-1,125,170,245,-1} },
  { {-1,-1,350,-1,-1}, {-1,375,420,495,-1}, {600,625,700,825,1000} }
};
constexpr int ROFFT[3][3] = {{0,64,128},{192,256,448},{640,704,896}};
constexpr int FOFFT[3]   = {0,8,32};

__device__ const double d_fact[11] = {1.,1.,2.,6.,24.,120.,720.,5040.,40320.,362880.,3628800.};

// ---------------------------------------------------------------------------
// Wigner 3j (complex basis, Racah) in double precision + real change of basis
// ---------------------------------------------------------------------------
__device__ double w3j_entry(int j1,int j2,int j3,int m1,int m2,int m3){
  if (m1+m2+m3 != 0) return 0.0;
  int dj = j1-j2; if (dj<0) dj=-dj;
  if (j3 < dj || j3 > j1+j2) return 0.0;
  int t1 = j2 - m1 - j3, t2 = j1 + m2 - j3;
  int kmin = 0; if (t1>kmin) kmin=t1; if (t2>kmin) kmin=t2;
  int kmax = j1+j2-j3; if (j1-m1<kmax) kmax=j1-m1; if (j2+m2<kmax) kmax=j2+m2;
  double s = 0.0;
  for (int k=kmin;k<=kmax;++k){
    double den = d_fact[k]*d_fact[k-t1]*d_fact[k-t2]*d_fact[j1+j2-j3-k]
               * d_fact[j1-m1-k]*d_fact[j2+m2-k];
    s += ((k&1)? -1.0:1.0)/den;
  }
  double pref = sqrt(d_fact[j1+j2-j3]*d_fact[j1-j2+j3]*d_fact[-j1+j2+j3]/d_fact[j1+j2+j3+1]
               * d_fact[j1+m1]*d_fact[j1-m1]*d_fact[j2+m2]*d_fact[j2-m2]
               * d_fact[j3+m3]*d_fact[j3-m3]);
  int ex = j1-j2-m3;
  if (ex & 1) pref = -pref;
  return pref*s;
}

__device__ void cob(int l, int r, int c, double& re, double& im){
  re = 0.0; im = 0.0;
  int mr = r - l, mc = c - l;
  const double s = 0.70710678118654752440;
  if (mr == 0) { if (mc == 0) re = 1.0; return; }
  if (mr > 0) {
    if (mc == mr)       re = (mr & 1) ? -s : s;
    else if (mc == -mr) re = s;
  } else {
    int m = -mr;
    if (mc == -m)      im = s;
    else if (mc == m)  im = (m & 1) ? s : -s;
  }
}

// ---------------------------------------------------------------------------
// Merged init: blocks 0..18 build+normalize one C3 chunk (wave 0 active);
// blocks 19.. repack W3t/W1t/W2t into the fragment-contiguous layout:
//   W3t elem idx = chunk*8192 + ((ct*4+ks)*64 + lane)*8 + j
//     encodes row r = ct*16+(lane&15), k = ks*32+(lane>>4)*8+j.
//   W1t/W2t elem idx = ((ot*4+ks)*64 + lane)*8 + j  (ot=0..6).
// 0.1 scale folded; k>=100 / o>=100 zero-padded.
// ---------------------------------------------------------------------------
__global__ __launch_bounds__(256) void init_kernel(
    const float* __restrict__ W3, const float* __restrict__ W1,
    const float* __restrict__ W2, __hip_bfloat16* __restrict__ W3t,
    __hip_bfloat16* __restrict__ W1t, __hip_bfloat16* __restrict__ W2t,
    float* __restrict__ C3f)
{
  if (blockIdx.x < NCOMBO){
    __shared__ double sre[225], sim[225];
    const int c = blockIdx.x;
    const int lo = CB_LO[c], li = CB_LI[c], lf = CB_LF[c];
    const int off = CB_OFF[c], sz = CB_SZ[c];
    const int n2 = 2*li+1, n3 = 2*lf+1;
    const int t = threadIdx.x;

    if (t < 64){
      for (int p=t; p<sz; p+=64){
        int a = p/(n2*n3), b = (p/n3)%n2, g = p%n3;
        double re=0.0, im=0.0;
        for (int m1=-lo; m1<=lo; ++m1){
          for (int m2=-li; m2<=li; ++m2){
            int m3 = -m1-m2;
            if (m3 < -lf || m3 > lf) continue;
            double w = w3j_entry(lo,li,lf,m1,m2,m3);
            if (w == 0.0) continue;
            double r1,i1,r2,i2,r3,i3;
            cob(lo, a, m1+lo, r1,i1);
            cob(li, b, m2+li, r2,i2);
            cob(lf, g, m3+lf, r3,i3);
            double rr = r1*r2 - i1*i2, ri = r1*i2 + i1*r2;
            double fr = rr*r3 - ri*i3, fi = rr*i3 + ri*r3;
            re += fr*w; im += fi*w;
          }
        }
        sre[p] = re; sim[p] = im;
      }
    }
    __syncthreads();
    if (t < 64){
      double s2r=0.0, s2i=0.0;
      for (int p=t; p<sz; p+=64){ double x=sre[p], y=sim[p]; s2r+=x*x; s2i+=y*y; }
      for (int m=1; m<64; m<<=1){ s2r += __shfl_xor(s2r, m, 64); s2i += __shfl_xor(s2i, m, 64); }
      bool useRe = (s2r >= s2i);
      double n = sqrt(useRe ? s2r : s2i);
      double inv = (n > 0.0) ? 1.0/n : 1.0;
      for (int p=t; p<sz; p+=64){
        double v = useRe ? sre[p] : sim[p];
        C3f[off+p] = (float)(v*inv);
      }
    }
    return;
  }

  int idx = (blockIdx.x - NCOMBO)*256 + threadIdx.x;
  constexpr int NW3 = 19*8192;       // 155648
  constexpr int HALF = 7*4*64*8;     // 14336
  if (idx < NW3){
    int j = idx & 7, lane = (idx>>3)&63, kc = (idx>>9)&15, chunk = idx>>13;
    int ks = kc & 3, ct = kc >> 2;
    int r = ct*16 + (lane&15);
    int k = ks*32 + (lane>>4)*8 + j;
    int lo = CB_LO[chunk], li = CB_LI[chunk], lf = CB_LF[chunk];
    int lmin = lo<li ? lo : li;
    int nlf = 2*lmin+1;
    int fi = lf - (lo>li ? lo-li : li-lo);
    int c = ROFFT[lo][li] + r*nlf + fi;
    float v = (k < 100) ? 0.1f*W3[(size_t)k*NCOL + c] : 0.f;
    W3t[idx] = __float2bfloat16(v);
  } else if (idx < NW3 + 2*HALF){
    int r2 = idx - NW3;
    const float* W = (r2 < HALF) ? W1 : W2;
    __hip_bfloat16* Wt = (r2 < HALF) ? W1t : W2t;
    int r = (r2 < HALF) ? r2 : r2 - HALF;
    int j = r & 7, lane = (r>>3)&63, kc = r>>9;   // kc = ot*4+ks in 0..27
    int ks = kc & 3, ot = kc >> 2;
    int o = ot*16 + (lane&15);
    int k = ks*32 + (lane>>4)*8 + j;
    float v = (o < 100 && k < 100) ? 0.1f*W[k*100+o] : 0.f;
    Wt[r] = __float2bfloat16(v);
  }
}

// ---------------------------------------------------------------------------
// Fused radial + GEMM + TP + atomic scatter-add. LDS 58916 B, 2 blocks/CU.
// Phase loop is __syncthreads-FREE (state wave-local; A-fragments global,
// C3 in LDS, rsh row + F row in registers).
// ---------------------------------------------------------------------------
constexpr int OF_RT  = 0;         // 64*68 f32 = 17408
constexpr int OF_ACC = 17408;     // 64*40 f32 = 10240 (live LO-group slice)
constexpr int OF_F   = 27648;     // 64*76 f32 = 19456
constexpr int OF_KV  = 47104;     // 64*25 f32 = 6400
constexpr int OF_C3  = 53504;     // 1225 f32 = 4900
constexpr int OF_SRC = 58404;     // 64 int = 256
constexpr int OF_TGT = 58660;     // 64 int = 256
constexpr int SMEM_SZ = 58916;

// radial overlay (prologue only; fused buffers dead then)
constexpr int OF_BAS  = 0;        // 640 f32 = 2560
constexpr int OF_HA   = 2560;     // 64*136 bf16 = 17408
constexpr int OF_HB   = 19968;    // 64*136 bf16 = 17408 -> ends 37376

__device__ __forceinline__ float swishf(float s){
  return SWISH_SCALE * s / (1.f + __expf(-s));
}

// radial MFMA layer, A-fragments coalesced from global (fragment-contiguous)
__device__ __forceinline__ void radial_layer_glb(
    const __hip_bfloat16* __restrict__ sIn,   // [64][136] bf16 LDS, rows e
    const __hip_bfloat16* __restrict__ Wt,    // global, fragment-permuted
    __hip_bfloat16* __restrict__ sOut,        // [64][136] bf16 LDS
    int lane, int wv, int lr, int lq)
{
  bf16x8 bf[4];
  #pragma unroll
  for (int ks=0; ks<4; ++ks)
    bf[ks] = *(const bf16x8*)&sIn[(wv*16+lr)*136 + ks*32 + lq*8];
  f32x4 acc[7] = {};
  #pragma unroll
  for (int ks=0; ks<4; ++ks)
    #pragma unroll
    for (int ot=0; ot<7; ++ot){
      bf16x8 a = *(const bf16x8*)&Wt[((ot*4+ks)*64 + lane)*8];
      acc[ot] = __builtin_amdgcn_mfma_f32_16x16x32_bf16(a, bf[ks], acc[ot], 0, 0, 0);
    }
  // C frag: col(lr)=e within wave, row(ot*16+lq*4+r)=o.  swish + bf16 + short4.
  #pragma unroll
  for (int ot=0; ot<7; ++ot){
    __hip_bfloat16 hv[4];
    #pragma unroll
    for (int r=0; r<4; ++r)
      hv[r] = __float2bfloat16(swishf(acc[ot][r]));   // Wt rows o>=100 zero -> swish(0)=0
    *(short4*)&sOut[(wv*16+lr)*136 + ot*16 + lq*4] = *(short4*)hv;
  }
  // zero k = 112..127 of own rows COMPLETELY: 64 lanes = 16 rows x 4 quarters
  {
    int l2 = lq*16 + lr;              // 0..63
    int row = l2 & 15, q = l2 >> 4;   // q in 0..3
    short4 z = {0,0,0,0};
    *(short4*)&sOut[(wv*16+row)*136 + 112 + q*4] = z;
  }
}

template<int LO,int LI,int LF>
__device__ __forceinline__ void kv_sec(float* kvb, const float* sC3,
                                       const float (&rr)[25],
                                       int e, int role)
{
  constexpr int NO = 2*LO+1, NI = 2*LI+1, NF = 2*LF+1;
  constexpr int C3B = C3OFFT[LO][LI][LF];
  for (int it = role; it < NO*NI; it += 4){
    float s = 0.f;
    #pragma unroll
    for (int mf=0; mf<NF; ++mf) s += sC3[C3B + it*NF + mf] * rr[LF*LF + mf];
    kvb[e*25 + it] = s;
  }
}

// consume with F in registers: all fv indices constexpr after unrolling.
template<int LO,int LI>
__device__ __forceinline__ void consume_sec(
    const float* sRt, const float (&fv)[72], const float* kvb, float* sAcc,
    int e, int role)
{
  constexpr int NO = 2*LO+1, NI = 2*LI+1;
  constexpr int FO = FOFFT[LI];
  float H[2][NI];
  #pragma unroll
  for (int du=0; du<2; ++du)
    #pragma unroll
    for (int mi=0; mi<NI; ++mi) H[du][mi] = 0.f;

  #pragma unroll
  for (int vg=0; vg<2; ++vg){
    #pragma unroll
    for (int du=0; du<2; ++du){
      const int u = role*2 + du;
      f32x4 rv = *(const f32x4*)&sRt[e*68 + u*8 + vg*4];
      #pragma unroll
      for (int v=0; v<4; ++v)
        #pragma unroll
        for (int mi=0; mi<NI; ++mi)
          H[du][mi] += rv[v] * fv[FO + vg*4*NI + v*NI + mi];
    }
  }
  // accumulate into group-local LDS slice (pitch 40):
  // LO=0: col=u (0..7); LO=1: col=u*3+o (0..23); LO=2: col=u*5+o (0..39)
  const int u0 = role*2, u1 = role*2 + 1;
  const int b0 = e*40 + ((LO==0) ? u0 : (LO==1) ? u0*3 : u0*5);
  const int b1 = e*40 + ((LO==0) ? u1 : (LO==1) ? u1*3 : u1*5);
  #pragma unroll
  for (int o=0; o<NO; ++o){
    float s0 = 0.f, s1 = 0.f;
    #pragma unroll
    for (int mi=0; mi<NI; ++mi){
      float kvv = kvb[e*25 + o*NI + mi];
      s0 += kvv * H[0][mi];
      s1 += kvv * H[1][mi];
    }
    sAcc[b0 + o] += s0;
    sAcc[b1 + o] += s1;
  }
}

// wave-local MFMA, A-fragments coalesced from global; setprio'd (T5).
__device__ __forceinline__ void mfma_sec_glb(
    const __hip_bfloat16* __restrict__ gW,    // W3t + chunk*8192
    float* sRt, const bf16x8 (&hf)[4],
    int lane, int wv, int lr, int lq)
{
  f32x4 a4[4] = {};
  __builtin_amdgcn_s_setprio(1);
  #pragma unroll
  for (int ks=0; ks<4; ++ks){
    #pragma unroll
    for (int ct=0; ct<4; ++ct){
      bf16x8 a = *(const bf16x8*)&gW[((ct*4+ks)*64 + lane)*8];
      a4[ct] = __builtin_amdgcn_mfma_f32_16x16x32_bf16(a, hf[ks], a4[ct], 0, 0, 0);
    }
  }
  __builtin_amdgcn_s_setprio(0);
  #pragma unroll
  for (int ct=0; ct<4; ++ct)
    *(f32x4*)&sRt[(wv*16 + lr)*68 + ct*16 + lq*4] = a4[ct];
}

// Wave-local flush: atomic scatter-add of the LO-group slice into out.
template<int J0,int W>
__device__ __forceinline__ void flush_group(float* sAcc, float* __restrict__ out,
                                            const int* sTgt, int eb, int t,
                                            float nrm, int E)
{
  const int lane = t & 63, wv = t >> 6;
  __builtin_amdgcn_wave_barrier();
  for (int p = lane; p < 16*W; p += 64){
    int el = wv*16 + p/W, j = p%W;
    if (eb + el < E)
      atomicAdd(&out[(size_t)sTgt[el]*FEATD + J0 + j], nrm * sAcc[el*40 + j]);
    sAcc[el*40 + j] = 0.f;                 // ready for next group
  }
  __builtin_amdgcn_wave_barrier();
}

// One phase, fully wave-local, NO block barriers:
// kv -> MFMA(global frags) -> wave_barrier -> consume -> wave_barrier.
template<int LO,int LI,int LF>
__device__ __forceinline__ void phase(
    int chunk, const __hip_bfloat16* __restrict__ W3t, const bf16x8 (&hf)[4],
    float* sRt, const float (&fv)[72], float* sKV, const float* sC3,
    const float (&rr)[25], float* sAcc, int t)
{
  const int e = t >> 2, role = t & 3;
  const int lane = t & 63, wv = t >> 6;
  const int lr = lane & 15, lq = lane >> 4;

  kv_sec<LO,LI,LF>(sKV, sC3, rr, e, role);
  mfma_sec_glb(W3t + (size_t)chunk*8192, sRt, hf, lane, wv, lr, lq);
  __builtin_amdgcn_wave_barrier();
  consume_sec<LO,LI>(sRt, fv, sKV, sAcc, e, role);
  __builtin_amdgcn_wave_barrier();
}

__global__ __launch_bounds__(256,2) void fused_kernel(
    const float* __restrict__ feats, const int* __restrict__ ei,
    const float* __restrict__ radii, const float* __restrict__ rsh,
    const float* __restrict__ W0,
    const __hip_bfloat16* __restrict__ W1t, const __hip_bfloat16* __restrict__ W2t,
    const __hip_bfloat16* __restrict__ W3t, const float* __restrict__ C3g,
    float* __restrict__ out, int E)
{
  __shared__ __align__(16) char smem[SMEM_SZ];
  // fused-view pointers
  float* sRt  = (float*)(smem + OF_RT);
  float* sAcc = (float*)(smem + OF_ACC);
  float* sFf  = (float*)(smem + OF_F);
  float* sKV  = (float*)(smem + OF_KV);
  float* sC3  = (float*)(smem + OF_C3);
  int*   sSrc = (int*)(smem + OF_SRC);
  int*   sTgt = (int*)(smem + OF_TGT);
  // radial-overlay pointers (prologue only)
  float* sbas = (float*)(smem + OF_BAS);
  __hip_bfloat16* hA = (__hip_bfloat16*)(smem + OF_HA);
  __hip_bfloat16* hB = (__hip_bfloat16*)(smem + OF_HB);

  const int t = threadIdx.x;
  const int eb = blockIdx.x*64;
  const int lane = t & 63, wv = t >> 6;
  const int lr = lane & 15, lq = lane >> 4;

  // ===================== radial prologue (barrier-light) ===================
  for (int p=t; p<640; p+=256){
    int er = p/10, k = p%10;
    int eg = eb + er;
    float r = (eg < E) ? radii[eg] : 0.f;
    float c = 0.7f + (2.5f/9.0f)*(float)k;
    float d = (r - c) * (9.0f/2.5f);
    sbas[p] = __expf(-d*d);
  }
  __syncthreads();
  // layer 1 (K=10, VALU), h1 bf16 into hA; zero k-pad 100..135
  for (int p=t; p<6400; p+=256){
    int er = p/100, o = p%100;
    float s = 0.f;
    #pragma unroll
    for (int k=0;k<10;++k) s += sbas[er*10+k]*W0[k*100+o];
    hA[er*136+o] = __float2bfloat16(swishf(s*0.3162277660168379f));   // 1/sqrt(10)
  }
  for (int p=t; p<64*36; p+=256){
    int er = p/36, k = 100 + p%36;
    hA[er*136+k] = __float2bfloat16(0.f);
  }
  __syncthreads();   // hA (cross-wave writes) ready

  radial_layer_glb(hA, W1t, hB, lane, wv, lr, lq);   // h2 (own rows)
  __builtin_amdgcn_wave_barrier();
  radial_layer_glb(hB, W2t, hA, lane, wv, lr, lq);   // h3 (own rows)
  __builtin_amdgcn_wave_barrier();

  // B-fragments straight from LDS (own wave rows)
  bf16x8 hf[4];
  #pragma unroll
  for (int ks=0; ks<4; ++ks)
    hf[ks] = *(const bf16x8*)&hA[(wv*16+lr)*136 + ks*32 + lq*8];

  __syncthreads();   // radial overlay dead; fused buffers may now be written

  // ===================== fused init ========================================
  for (int p=t; p<2560; p+=256) sAcc[p] = 0.f;
  for (int p=t; p<64; p+=256){
    int e = eb + p;
    sSrc[p] = (e < E) ? ei[e] : 0;
    sTgt[p] = (e < E) ? ei[E + e] : 0;
  }
  for (int p=t; p<C3TOT; p+=256) sC3[p] = C3g[p];
  __syncthreads();
  for (int p=t; p<64*72; p+=256){
    int el = p/72, j = p%72;
    sFf[el*76 + j] = feats[(size_t)sSrc[el]*72 + j];
  }
  __syncthreads();   // LAST block barrier — phase loop below is barrier-free

  // own-edge rsh row -> 25 registers; own-edge F row -> 72 registers
  int eg = eb + (t >> 2); if (eg > E-1) eg = E-1;
  const float* rshrow = rsh + (size_t)eg*25;
  float rr[25];
  #pragma unroll
  for (int mf=0; mf<25; ++mf) rr[mf] = rshrow[mf];
  float fv[72];
  {
    const int e = t >> 2;
    #pragma unroll
    for (int q=0; q<18; ++q)
      *(f32x4*)&fv[q*4] = *(const f32x4*)&sFf[e*76 + q*4];
  }

  // ---- group LO=0: output cols 0..7 ----
  phase<0,0,0>( 0, W3t, hf, sRt, fv, sKV, sC3, rr, sAcc, t);
  phase<0,1,1>( 1, W3t, hf, sRt, fv, sKV, sC3, rr, sAcc, t);
  phase<0,2,2>( 2, W3t, hf, sRt, fv, sKV, sC3, rr, sAcc, t);
  flush_group<0,8>(sAcc, out, sTgt, eb, t, 0.72360125f, E);

  // ---- group LO=1: output cols 8..31 ----
  phase<1,0,1>( 3, W3t, hf, sRt, fv, sKV, sC3, rr, sAcc, t);
  phase<1,1,0>( 4, W3t, hf, sRt, fv, sKV, sC3, rr, sAcc, t);
  phase<1,1,1>( 5, W3t, hf, sRt, fv, sKV, sC3, rr, sAcc, t);
  phase<1,1,2>( 6, W3t, hf, sRt, fv, sKV, sC3, rr, sAcc, t);
  phase<1,2,1>( 7, W3t, hf, sRt, fv, sKV, sC3, rr, sAcc, t);
  phase<1,2,2>( 8, W3t, hf, sRt, fv, sKV, sC3, rr, sAcc, t);
  phase<1,2,3>( 9, W3t, hf, sRt, fv, sKV, sC3, rr, sAcc, t);
  flush_group<8,24>(sAcc, out, sTgt, eb, t, 0.8204867f, E);

  // ---- group LO=2: output cols 32..71 ----
  phase<2,0,2>(10, W3t, hf, sRt, fv, sKV, sC3, rr, sAcc, t);
  phase<2,1,1>(11, W3t, hf, sRt, fv, sKV, sC3, rr, sAcc, t);
  phase<2,1,2>(12, W3t, hf, sRt, fv, sKV, sC3, rr, sAcc, t);
  phase<2,1,3>(13, W3t, hf, sRt, fv, sKV, sC3, rr, sAcc, t);
  phase<2,2,0>(14, W3t, hf, sRt, fv, sKV, sC3, rr, sAcc, t);
  phase<2,2,1>(15, W3t, hf, sRt, fv, sKV, sC3, rr, sAcc, t);
  phase<2,2,2>(16, W3t, hf, sRt, fv, sKV, sC3, rr, sAcc, t);
  phase<2,2,3>(17, W3t, hf, sRt, fv, sKV, sC3, rr, sAcc, t);
  phase<2,2,4>(18, W3t, hf, sRt, fv, sKV, sC3, rr, sAcc, t);
  flush_group<32,40>(sAcc, out, sTgt, eb, t, 0.9341652f, E);
}

// ---------------------------------------------------------------------------
extern "C" void kernel_launch(void* const* d_in, const int* in_sizes, int n_in,
                              void* d_out, int out_size, void* d_ws, size_t ws_size,
                              hipStream_t stream)
{
  const float* feats = (const float*)d_in[0];
  const int*   ei    = (const int*)d_in[1];
  const float* radii = (const float*)d_in[2];
  const float* rsh   = (const float*)d_in[3];
  const float* W0    = (const float*)d_in[4];
  const float* W1    = (const float*)d_in[5];
  const float* W2    = (const float*)d_in[6];
  const float* W3    = (const float*)d_in[7];
  float* out = (float*)d_out;
  const int E = in_sizes[2];

  const int EPAD = ((E + 63)/64)*64;
  const int NBLK = EPAD/64;

  char* ws = (char*)d_ws;
  size_t off_b = 0;
  float*  C3f = (float*)(ws + off_b);  off_b += 8192;
  __hip_bfloat16* W3t = (__hip_bfloat16*)(ws + off_b); off_b += 335872;  // 19*16KB used
  __hip_bfloat16* W1t = (__hip_bfloat16*)(ws + off_b); off_b += 30720;   // 14336 elems used
  __hip_bfloat16* W2t = (__hip_bfloat16*)(ws + off_b); off_b += 30720;

  // out accumulates via atomics -> zero it inside the graph
  hipMemsetAsync(out, 0, (size_t)out_size*sizeof(float), stream);

  // merged constants/tables: 19 c3 blocks + 720 repack blocks
  constexpr int PREP_BLKS = (19*8192 + 2*14336 + 255)/256;   // 720
  init_kernel<<<dim3(NCOMBO + PREP_BLKS), dim3(256), 0, stream>>>(
      W3, W1, W2, W3t, W1t, W2t, C3f);

  // main pipeline: fused radial + GEMM + TP + atomic scatter-add
  fused_kernel<<<dim3(NBLK), dim3(256), 0, stream>>>(
      feats, ei, radii, rsh, W0, W1t, W2t, W3t, C3f, out, E);
}